// Round 1
// 301.218 us; speedup vs baseline: 1.0342x; 1.0342x over previous
//
#include <hip/hip_runtime.h>

// Bilinear 4x upsample (depthwise conv_transpose2d, stride=4, 7x7 bilinear taps).
// in  x: [4,256,64,64] fp32 ; out: [4,256,259,259] fp32
//
// Convention (verified against conv_general_dilated with lhs_dilation=4,
// padding=k-1=6): out row oy=4q+py taps input rows q-1 (w=.25*(3-py)) and
// q (w=.25*(py+1)); separable, identical weights in x:
//   out col ox taps cols (ox>>2)-1, (ox>>2) with w=(.25*(3-px), .25*(px+1)),
//   px = ox&3.
//
// R4 structure: one WAVE owns (nc, strip of 8 q-values), rolling register
// row pair (xl=row q-1, xh=row q) + prefetch. Key change vs R3: lane L
// stores the UNALIGNED float4 at ox=4L (gfx950 global_store_dwordx4 only
// needs dword alignment), so the horizontal taps are exactly
// (A=V[lane-1], B=V[lane]) and the 4 outputs are an averaging ladder:
//   e1=.5(A+B), e0=.5(A+e1), e2=.5(e1+B), e3=B.
// This removes the 52-register weight/select tables, the down-shuffle, all
// cndmasks, and the divergent scalar row tails (lane 63 writes the 3-float
// tail as one overlapping float4 at row+255; element 255 is rewritten with
// the same value). Expect ~40 VGPR -> 8 waves/SIMD (one full residency of
// 8192 waves).

#define IH 64
#define IW 64
#define OH 259
#define OW 259
#define OROW 67081  // OH*OW

typedef float float4u __attribute__((ext_vector_type(4), aligned(4)));

__global__ __launch_bounds__(256) void upsample4x_strip(
    const float* __restrict__ x, float* __restrict__ out)
{
    const int lane  = threadIdx.x & 63;
    const int g     = blockIdx.x * 4 + (threadIdx.x >> 6);  // global wave id
    const int strip = g & 7;                                 // 0..7
    const int nc    = g >> 3;                                // 0..1023

    const int q0 = strip * 8;
    const int q1 = (strip == 7) ? 65 : q0 + 8;  // strip 7 also handles q=64

    const float* __restrict__ xp = x + (size_t)nc * (IH * IW);
    float* __restrict__ ob = out + (size_t)nc * OROW;

    // rolling input rows (register-resident); 0 => tap dropped at the edge
    float xl = (q0 == 0) ? 0.0f : xp[(q0 - 1) * IW + lane];  // row q0-1
    float xh = xp[q0 * IW + lane];                            // row q0
    float xlm = __shfl_up(xl, 1); if (lane == 0) xlm = 0.0f;  // col lane-1
    float xhm = __shfl_up(xh, 1); if (lane == 0) xhm = 0.0f;

    for (int q = q0; q < q1; ++q) {
        // prefetch row q+1 (q=64 -> 0 => hi tap dropped)
        const int qn = q + 1;
        float xn = 0.0f;
        if (qn < q1 && qn < IH) xn = xp[qn * IW + lane];

#pragma unroll
        for (int py = 0; py < 4; ++py) {
            const int oy = 4 * q + py;
            if (oy < OH) {                       // false only for q==64, py==3
                const float wyl = 0.25f * (float)(3 - py);
                const float wyh = 0.25f * (float)(py + 1);
                float B = wyl * xl  + wyh * xh;   // vertical combo, col lane
                float A = wyl * xlm + wyh * xhm;  // col lane-1 (0 at lane 0)

                float e1 = 0.5f * (A + B);        // px=1: .5A+.5B
                float e0 = 0.5f * (A + e1);       // px=0: .75A+.25B
                float e2 = 0.5f * (e1 + B);       // px=2: .25A+.75B
                                                  // px=3: B

                float* rp = ob + (size_t)oy * OW;
                float4u v = {e0, e1, e2, B};
                ((float4u*)rp)[lane] = v;         // ox = 4*lane .. 4*lane+3

                if (lane == 63) {
                    // ox=255..258: {B(dup), .75B, .5B, .25B} (col-64 tap dropped)
                    float4u t = {B, 0.75f * B, 0.5f * B, 0.25f * B};
                    *(float4u*)(rp + 255) = t;
                }
            }
        }

        // roll rows: q-1 <- q, q <- q+1
        xl = xh; xlm = xhm;
        xh = xn;
        xhm = __shfl_up(xh, 1); if (lane == 0) xhm = 0.0f;
    }
}

extern "C" void kernel_launch(void* const* d_in, const int* in_sizes, int n_in,
                              void* d_out, int out_size, void* d_ws, size_t ws_size,
                              hipStream_t stream)
{
    const float* x = (const float*)d_in[0];
    // d_in[1] (weight) is the fixed bilinear kernel; taps are hardcoded exactly.
    float* out = (float*)d_out;

    // 1024 nc * 8 strips = 8192 waves = 2048 blocks of 4 waves
    upsample4x_strip<<<2048, 256, 0, stream>>>(x, out);
}

// Round 2
// 294.171 us; speedup vs baseline: 1.0589x; 1.0240x over previous
//
#include <hip/hip_runtime.h>

// Bilinear 4x upsample (depthwise conv_transpose2d, stride=4, 7x7 bilinear taps).
// in  x: [4,256,64,64] fp32 ; out: [4,256,259,259] fp32
//
// out row oy=4q+py taps input rows q-1 (w=.25*(3-py)) and q (w=.25*(py+1));
// separable, same weights in x: out col ox taps cols (ox>>2)-1, (ox>>2)
// with w=(.25*(3-px), .25*(px+1)), px=ox&3.
//
// R5 structure: one WAVE owns (nc, strip of 8-9 q-values). ALL 10 input rows
// the strip needs are loaded up front (10 independent coalesced dword loads
// -> ONE memory latency per wave instead of one per q-iteration; R4 stalled
// ~500 cyc/iter on its rolling prefetch). Then the q-loop is pure
// compute+store: lane L stores the unaligned float4 at ox=4L (dword-aligned
// dwordx4 is legal on gfx950), taps are (A=V[lane-1], B=V[lane]), averaging
// ladder e1=.5(A+B), e0=.5(A+e1), e2=.5(e1+B), e3=B. Lane 63 writes the
// 3-float row tail as one overlapping float4 at row+255 (elem 255 rewritten
// with the same value). Fully unrolled j-loop -> all row-array indices static
// (runtime-indexed arrays would spill to scratch).

#define IH 64
#define IW 64
#define OH 259
#define OW 259
#define OROW 67081  // OH*OW

typedef float float4u __attribute__((ext_vector_type(4), aligned(4)));

__global__ __launch_bounds__(256) void upsample4x_strip(
    const float* __restrict__ x, float* __restrict__ out)
{
    const int lane  = threadIdx.x & 63;
    const int g     = blockIdx.x * 4 + (threadIdx.x >> 6);  // global wave id
    const int strip = g & 7;                                 // 0..7
    const int nc    = g >> 3;                                // 0..1023

    const int q0 = strip * 8;
    const int q1 = (strip == 7) ? 65 : q0 + 8;  // strip 7 also handles q=64

    const float* __restrict__ xp = x + (size_t)nc * (IH * IW);
    float* __restrict__ ob = out + (size_t)nc * OROW;

    // --- load ALL rows this strip needs: rows q0-1 .. q0+8 (OOB -> 0) ---
    float r[10], rm[10];
#pragma unroll
    for (int i = 0; i < 10; ++i) {
        const int ri = q0 - 1 + i;
        r[i] = (ri >= 0 && ri < IH) ? xp[ri * IW + lane] : 0.0f;
    }
#pragma unroll
    for (int i = 0; i < 10; ++i) {
        rm[i] = __shfl_up(r[i], 1);
        if (lane == 0) rm[i] = 0.0f;            // col -1 tap dropped
    }

    // --- 8 (or 9) q-iterations, fully unrolled, static row indices ---
#pragma unroll
    for (int j = 0; j < 9; ++j) {
        const int q = q0 + j;
        if (q < q1) {
            const float xl  = r[j],     xh  = r[j + 1];   // rows q-1, q
            const float xlm = rm[j],    xhm = rm[j + 1];

#pragma unroll
            for (int py = 0; py < 4; ++py) {
                const int oy = 4 * q + py;
                if (oy < OH) {                   // false only for q==64, py==3
                    const float wyl = 0.25f * (float)(3 - py);
                    const float wyh = 0.25f * (float)(py + 1);
                    float B = wyl * xl  + wyh * xh;   // vertical combo, col lane
                    float A = wyl * xlm + wyh * xhm;  // col lane-1 (0 at lane 0)

                    float e1 = 0.5f * (A + B);        // px=1
                    float e0 = 0.5f * (A + e1);       // px=0: .75A+.25B
                    float e2 = 0.5f * (e1 + B);       // px=2: .25A+.75B
                                                      // px=3: B

                    float* rp = ob + (size_t)oy * OW;
                    float4u v = {e0, e1, e2, B};
                    ((float4u*)rp)[lane] = v;         // ox = 4*lane .. 4*lane+3

                    if (lane == 63) {
                        // ox=255..258: {B(dup), .75B, .5B, .25B} (col 64 dropped)
                        float4u t = {B, 0.75f * B, 0.5f * B, 0.25f * B};
                        *(float4u*)(rp + 255) = t;
                    }
                }
            }
        }
    }
}

extern "C" void kernel_launch(void* const* d_in, const int* in_sizes, int n_in,
                              void* d_out, int out_size, void* d_ws, size_t ws_size,
                              hipStream_t stream)
{
    const float* x = (const float*)d_in[0];
    // d_in[1] (weight) is the fixed bilinear kernel; taps are hardcoded exactly.
    float* out = (float*)d_out;

    // 1024 nc * 8 strips = 8192 waves = 2048 blocks of 4 waves (1 residency)
    upsample4x_strip<<<2048, 256, 0, stream>>>(x, out);
}